// Round 7
// baseline (652.180 us; speedup 1.0000x reference)
//
#include <hip/hip_runtime.h>
#include <stdint.h>

#define N_NODES 50000
#define N_EDGES 800000
#define CAP 80        // bucket capacity; deg ~ Poisson(16), P(deg>80) ~ 1e-25
#define ZROW N_NODES  // zero-row index used to pad gather loops (rows 50000..50047 zeroed)
#define NFILT 98      // filter blocks: 98 x 512 nodes = 50176 covers nodes+pads
#define GEMM_BLOCKS 782   // 50048/64
// R7: 4-stage binned CSR pipeline (R5/R6: ~45us serial regardless of arrangement)
// collapsed to ONE filter-scatter stage: each of 98 blocks streams the whole dst
// array (3.2MB, L2-broadcast across blocks) and keeps its 512-node range. No
// histogram, no scan, no binscat, no inter-stage sync. Fused under gemm1.
// D_IN=128, H1=128, H2=64, C=2 — inputs fp32; intermediates bf16 (h1s UNscaled, h2s dinv-prescaled)

typedef __attribute__((ext_vector_type(8))) short short8;     // 8 bf16 (4 VGPRs)
typedef __attribute__((ext_vector_type(4))) float floatx4;    // MFMA acc

// ---------- bf16 helpers ----------
__device__ __forceinline__ float bflo(uint32_t u) { return __uint_as_float(u << 16); }
__device__ __forceinline__ float bfhi(uint32_t u) { return __uint_as_float(u & 0xffff0000u); }
__device__ __forceinline__ unsigned short f2b(float f) {
    uint32_t u = __float_as_uint(f);
    u += 0x7fffu + ((u >> 16) & 1u);   // RNE
    return (unsigned short)(u >> 16);
}

// ---------- 1. prep: Wt1/Wt2 bf16 transposes only (96 blocks) ----------
__global__ __launch_bounds__(256) void k_prep(const float* __restrict__ W1,
                                              const float* __restrict__ W2,
                                              unsigned short* __restrict__ Wt1,
                                              unsigned short* __restrict__ Wt2) {
    int gid = blockIdx.x * 256 + threadIdx.x;
    if (gid < 16384) {                     // Wt1[n][k] = bf16(W1[k][n])
        int k = gid >> 7, n = gid & 127;
        Wt1[n * 128 + k] = f2b(W1[gid]);
    } else if (gid < 24576) {              // Wt2[n][k] = bf16(W2[k][n])
        int j = gid - 16384;
        int k = j >> 6, n = j & 63;
        Wt2[n * 128 + k] = f2b(W2[j]);
    }
}

// ---------- 2. FUSED: filter-CSR (blocks 0..97) || gemm1 (98..879) ----------
// filter: block b owns nodes [b*512, b*512+512). Stream ALL dst (int4 coalesced;
// same stream for every block -> L2/L3 broadcast), keep hits (1/98), LDS-atomic
// rank, write csr rows (320B, disjoint 160KB window) + counts (pads = 0 free).
// gemm1: h1s[v] = bf16(x[v]) @ bf16(W1), UNSCALED; 64 rows/block; zeroes pad rows.
__global__ __launch_bounds__(256) void k_csr_gemm1(const int* __restrict__ src,
                                                   const int* __restrict__ dst,
                                                   int* __restrict__ counts,
                                                   int* __restrict__ csr,
                                                   const float* __restrict__ x,
                                                   const unsigned short* __restrict__ Wt1,
                                                   unsigned short* __restrict__ h1s,
                                                   unsigned short* __restrict__ h2s) {
    __shared__ unsigned short At[64 * 136];   // 17.0 KB (pad 8 bf16)
    __shared__ unsigned short Bt[128 * 136];  // 34.0 KB
    int t = threadIdx.x;
    if (blockIdx.x < NFILT) {
        int* cnt = (int*)At;                  // alias: 512 ints in At's LDS
        cnt[t] = 0; cnt[t + 256] = 0;
        __syncthreads();
        int node0 = blockIdx.x << 9;
        const int4* d4 = (const int4*)dst;
        // 200000 int4 records; threads 0..63 take the 64-element tail round
        for (int j = t; j < 200000; j += 256) {
            int4 dv = d4[j];
            unsigned o0 = (unsigned)(dv.x - node0);
            unsigned o1 = (unsigned)(dv.y - node0);
            unsigned o2 = (unsigned)(dv.z - node0);
            unsigned o3 = (unsigned)(dv.w - node0);
            if (o0 < 512u) { int r = atomicAdd(&cnt[o0], 1); if (r < CAP) csr[dv.x * CAP + r] = src[j * 4 + 0]; }
            if (o1 < 512u) { int r = atomicAdd(&cnt[o1], 1); if (r < CAP) csr[dv.y * CAP + r] = src[j * 4 + 1]; }
            if (o2 < 512u) { int r = atomicAdd(&cnt[o2], 1); if (r < CAP) csr[dv.z * CAP + r] = src[j * 4 + 2]; }
            if (o3 < 512u) { int r = atomicAdd(&cnt[o3], 1); if (r < CAP) csr[dv.w * CAP + r] = src[j * 4 + 3]; }
        }
        __syncthreads();
        counts[node0 + t] = cnt[t];           // covers all 50176 incl. zero pads
        counts[node0 + 256 + t] = cnt[t + 256];
        return;
    }
    // ---- gemm1 ----
    int row0 = (blockIdx.x - NFILT) * 64;
    for (int i = t; i < 2048; i += 256) {     // stage Bt (Wt1 [n][k] bf16)
        int n = i >> 4, kc = (i & 15) * 8;
        *(uint4*)&Bt[n * 136 + kc] = *(const uint4*)(Wt1 + n * 128 + kc);
    }
    for (int i = t; i < 1024; i += 256) {     // stage At: fp32 -> bf16
        int r = i >> 4, kc = (i & 15) * 8;
        int g = row0 + r; if (g >= N_NODES) g = N_NODES - 1;
        const float* p = x + g * 128 + kc;
        float4 a = *(const float4*)p, b = *(const float4*)(p + 4);
        uint4 o;
        o.x = (uint32_t)f2b(a.x) | ((uint32_t)f2b(a.y) << 16);
        o.y = (uint32_t)f2b(a.z) | ((uint32_t)f2b(a.w) << 16);
        o.z = (uint32_t)f2b(b.x) | ((uint32_t)f2b(b.y) << 16);
        o.w = (uint32_t)f2b(b.z) | ((uint32_t)f2b(b.w) << 16);
        *(uint4*)&At[r * 136 + kc] = o;
    }
    __syncthreads();
    int wv = t >> 6, lane = t & 63;
    int m = lane & 15, qd = lane >> 4;
    floatx4 acc[8];
    #pragma unroll
    for (int c = 0; c < 8; c++) acc[c] = (floatx4){0.f, 0.f, 0.f, 0.f};
    const unsigned short* ap = &At[(wv * 16 + m) * 136 + qd * 8];
    const unsigned short* bp = &Bt[m * 136 + qd * 8];
    #pragma unroll
    for (int kk = 0; kk < 4; kk++) {
        short8 af = *(const short8*)(ap + kk * 32);
        #pragma unroll
        for (int c = 0; c < 8; c++) {
            short8 bf = *(const short8*)(bp + c * 16 * 136 + kk * 32);
            acc[c] = __builtin_amdgcn_mfma_f32_16x16x32_bf16(af, bf, acc[c], 0, 0, 0);
        }
    }
    #pragma unroll
    for (int reg = 0; reg < 4; reg++) {       // D[row=qd*4+reg][col=16c+m]
        int g = row0 + wv * 16 + qd * 4 + reg;
        if (g < N_NODES) {
            #pragma unroll
            for (int c = 0; c < 8; c++)
                h1s[g * 128 + c * 16 + m] = f2b(acc[c][reg]);
        } else {                              // zero pad rows (branchless-agg target)
            #pragma unroll
            for (int c = 0; c < 8; c++)
                h1s[g * 128 + c * 16 + m] = 0;
            #pragma unroll
            for (int c = 0; c < 4; c++)
                h2s[g * 64 + c * 16 + m] = 0;
        }
    }
}

// ---------- 3. fused agg1 + GEMM2 (unchanged) ----------
__global__ __launch_bounds__(256) void k_agg1g2(const unsigned short* __restrict__ h1s,
                                                const unsigned short* __restrict__ Wt2,
                                                const int* __restrict__ csr,
                                                const int* __restrict__ counts,
                                                const float* __restrict__ b1,
                                                unsigned short* __restrict__ h2s) {
    __shared__ unsigned short Bt[64 * 136];   // Wt2 [n=64][k=128] staged
    __shared__ unsigned short At[16 * 136];   // r1 tile [16 rows][128 k]
    int t = threadIdx.x;
    for (int i = t; i < 1024; i += 256) {     // stage Bt2
        int n = i >> 4, kc = (i & 15) * 8;
        *(uint4*)&Bt[n * 136 + kc] = *(const uint4*)(Wt2 + n * 128 + kc);
    }
    int wv = t >> 6, lane = t & 63;
    int q = lane >> 4, l = lane & 15;
    int v0 = blockIdx.x * 16;
    int v = v0 + wv * 4 + q;                  // 50000 = 3125*16: always valid
    int n = counts[v];
    float dv = rsqrtf((float)n + 1.0f);
    int n_eff = min(n, CAP);
    const int* cs = csr + v * CAP;
    int nmax = n_eff;
    nmax = max(nmax, __shfl_xor(nmax, 16));
    nmax = max(nmax, __shfl_xor(nmax, 32));
    float a0, a1, a2, a3, a4, a5, a6, a7;
    {   // self-loop row: dv * h1s[v] (h1s unscaled)
        uint4 p = *(const uint4*)(h1s + v * 128 + l * 8);
        a0 = dv * bflo(p.x); a1 = dv * bfhi(p.x); a2 = dv * bflo(p.y); a3 = dv * bfhi(p.y);
        a4 = dv * bflo(p.z); a5 = dv * bfhi(p.z); a6 = dv * bflo(p.w); a7 = dv * bfhi(p.w);
    }
    for (int base = 0; base < nmax; base += 16) {
        int idx = base + l;
        int e = (idx < n_eff) ? cs[idx] : ZROW;     // pad -> zero row
        float de = rsqrtf((float)counts[e] + 1.0f); // counts[ZROW]=0 -> de=1, row=0
        int mm = nmax - base; if (mm > 16) mm = 16;
        #pragma unroll 4
        for (int i = 0; i < mm; i++) {
            int s = __shfl(e, (q << 4) + i);        // ZROW contributes exact 0.0f
            float di = __shfl(de, (q << 4) + i);
            uint4 p = *(const uint4*)(h1s + s * 128 + l * 8);
            a0 = fmaf(di, bflo(p.x), a0); a1 = fmaf(di, bfhi(p.x), a1);
            a2 = fmaf(di, bflo(p.y), a2); a3 = fmaf(di, bfhi(p.y), a3);
            a4 = fmaf(di, bflo(p.z), a4); a5 = fmaf(di, bfhi(p.z), a5);
            a6 = fmaf(di, bflo(p.w), a6); a7 = fmaf(di, bfhi(p.w), a7);
        }
    }
    {
        float4 bL = *(const float4*)(b1 + l * 8);
        float4 bH = *(const float4*)(b1 + l * 8 + 4);
        a0 = fmaxf(fmaf(dv, a0, bL.x), 0.f); a1 = fmaxf(fmaf(dv, a1, bL.y), 0.f);
        a2 = fmaxf(fmaf(dv, a2, bL.z), 0.f); a3 = fmaxf(fmaf(dv, a3, bL.w), 0.f);
        a4 = fmaxf(fmaf(dv, a4, bH.x), 0.f); a5 = fmaxf(fmaf(dv, a5, bH.y), 0.f);
        a6 = fmaxf(fmaf(dv, a6, bH.z), 0.f); a7 = fmaxf(fmaf(dv, a7, bH.w), 0.f);
        uint4 o;
        o.x = (uint32_t)f2b(a0) | ((uint32_t)f2b(a1) << 16);
        o.y = (uint32_t)f2b(a2) | ((uint32_t)f2b(a3) << 16);
        o.z = (uint32_t)f2b(a4) | ((uint32_t)f2b(a5) << 16);
        o.w = (uint32_t)f2b(a6) | ((uint32_t)f2b(a7) << 16);
        *(uint4*)&At[(wv * 4 + q) * 136 + l * 8] = o;   // r1 tile row
    }
    __syncthreads();
    // MFMA: wave wv -> col-tile wv (cols 16wv..16wv+15)
    int m = lane & 15, qd = lane >> 4;
    floatx4 acc = (floatx4){0.f, 0.f, 0.f, 0.f};
    const unsigned short* ap = &At[m * 136 + qd * 8];
    const unsigned short* bp = &Bt[(wv * 16 + m) * 136 + qd * 8];
    #pragma unroll
    for (int kk = 0; kk < 4; kk++) {
        short8 af = *(const short8*)(ap + kk * 32);
        short8 bf = *(const short8*)(bp + kk * 32);
        acc = __builtin_amdgcn_mfma_f32_16x16x32_bf16(af, bf, acc, 0, 0, 0);
    }
    #pragma unroll
    for (int reg = 0; reg < 4; reg++) {
        int g = v0 + qd * 4 + reg;
        float dg = rsqrtf((float)counts[g] + 1.0f);   // prescale h2 rows
        h2s[g * 64 + wv * 16 + m] = f2b(dg * acc[reg]);
    }
}

// ---------- 4. agg2 + head (2 neighbors/iter; unchanged) ----------
__global__ __launch_bounds__(256) void k_agg2(const unsigned short* __restrict__ h2s,
                                              const int* __restrict__ csr,
                                              const int* __restrict__ counts,
                                              const float* __restrict__ b2,
                                              const float* __restrict__ Wo,
                                              const float* __restrict__ bo,
                                              float* __restrict__ out) {
    int wave = (blockIdx.x * 256 + threadIdx.x) >> 6;
    int lane = threadIdx.x & 63;
    int q = lane >> 4, l = lane & 15;
    int h = l >> 3, c = l & 7;                // half, column-octet
    int v = wave * 4 + q;                     // 3125*4*4 = 50000: always valid
    int n = counts[v];
    float dv = rsqrtf((float)n + 1.0f);
    int n_eff = min(n, CAP);
    const int* cs = csr + v * CAP;
    int nmax = n_eff;
    nmax = max(nmax, __shfl_xor(nmax, 16));
    nmax = max(nmax, __shfl_xor(nmax, 32));
    float a0 = 0.f, a1 = 0.f, a2 = 0.f, a3 = 0.f, a4 = 0.f, a5 = 0.f, a6 = 0.f, a7 = 0.f;
    if (h == 0) {   // self-loop row (prescaled) into half 0 only
        uint4 p = *(const uint4*)(h2s + v * 64 + c * 8);
        a0 = bflo(p.x); a1 = bfhi(p.x); a2 = bflo(p.y); a3 = bfhi(p.y);
        a4 = bflo(p.z); a5 = bfhi(p.z); a6 = bflo(p.w); a7 = bfhi(p.w);
    }
    for (int base = 0; base < nmax; base += 16) {
        int idx = base + l;
        int e = (idx < n_eff) ? cs[idx] : ZROW;   // pad -> zero row (extra odd slot too)
        int mm = nmax - base; if (mm > 16) mm = 16;
        int pairs = (mm + 1) >> 1;
        #pragma unroll 4
        for (int i = 0; i < pairs; i++) {
            int s = __shfl(e, (q << 4) + 2 * i + h);   // half h takes pair element h
            uint4 p = *(const uint4*)(h2s + s * 64 + c * 8);
            a0 += bflo(p.x); a1 += bfhi(p.x); a2 += bflo(p.y); a3 += bfhi(p.y);
            a4 += bflo(p.z); a5 += bfhi(p.z); a6 += bflo(p.w); a7 += bfhi(p.w);
        }
    }
    // combine halves
    a0 += __shfl_xor(a0, 8); a1 += __shfl_xor(a1, 8);
    a2 += __shfl_xor(a2, 8); a3 += __shfl_xor(a3, 8);
    a4 += __shfl_xor(a4, 8); a5 += __shfl_xor(a5, 8);
    a6 += __shfl_xor(a6, 8); a7 += __shfl_xor(a7, 8);
    float4 bL = *(const float4*)(b2 + c * 8);
    float4 bH = *(const float4*)(b2 + c * 8 + 4);
    a0 = fmaxf(fmaf(dv, a0, bL.x), 0.f); a1 = fmaxf(fmaf(dv, a1, bL.y), 0.f);
    a2 = fmaxf(fmaf(dv, a2, bL.z), 0.f); a3 = fmaxf(fmaf(dv, a3, bL.w), 0.f);
    a4 = fmaxf(fmaf(dv, a4, bH.x), 0.f); a5 = fmaxf(fmaf(dv, a5, bH.y), 0.f);
    a6 = fmaxf(fmaf(dv, a6, bH.z), 0.f); a7 = fmaxf(fmaf(dv, a7, bH.w), 0.f);
    // head: logits over this lane's 8 cols (8c..8c+7), Wo row-major [64][2]
    float4 wA = *(const float4*)(Wo + c * 16);
    float4 wB = *(const float4*)(Wo + c * 16 + 4);
    float4 wC = *(const float4*)(Wo + c * 16 + 8);
    float4 wD = *(const float4*)(Wo + c * 16 + 12);
    float l0 = a0 * wA.x + a1 * wA.z + a2 * wB.x + a3 * wB.z
             + a4 * wC.x + a5 * wC.z + a6 * wD.x + a7 * wD.z;
    float l1 = a0 * wA.y + a1 * wA.w + a2 * wB.y + a3 * wB.w
             + a4 * wC.y + a5 * wC.w + a6 * wD.y + a7 * wD.w;
    l0 += __shfl_xor(l0, 1); l1 += __shfl_xor(l1, 1);
    l0 += __shfl_xor(l0, 2); l1 += __shfl_xor(l1, 2);
    l0 += __shfl_xor(l0, 4); l1 += __shfl_xor(l1, 4);
    if (l == 0) {
        float2 bof = *(const float2*)bo;
        l0 += bof.x; l1 += bof.y;
        float m = fmaxf(l0, l1);
        float ls = m + __logf(__expf(l0 - m) + __expf(l1 - m));
        *(float2*)(out + v * 2) = make_float2(l0 - ls, l1 - ls);
    }
}

extern "C" void kernel_launch(void* const* d_in, const int* in_sizes, int n_in,
                              void* d_out, int out_size, void* d_ws, size_t ws_size,
                              hipStream_t stream) {
    const float* x  = (const float*)d_in[0];
    const int* ei   = (const int*)d_in[1];
    const float* W1 = (const float*)d_in[2];
    const float* b1 = (const float*)d_in[3];
    const float* W2 = (const float*)d_in[4];
    const float* b2 = (const float*)d_in[5];
    const float* Wo = (const float*)d_in[6];
    const float* bo = (const float*)d_in[7];
    float* out      = (float*)d_out;
    const int* src = ei;             // edge_index[0]
    const int* dst = ei + N_EDGES;   // edge_index[1]

    char* w = (char*)d_ws;
    int* counts = (int*)(w + 0);                           // 200 KB (50176 ints; pads written 0 by filter)
    int* csr    = (int*)(w + 200704);                      // 16 MB  [node][CAP]
    unsigned short* Wt1 = (unsigned short*)(w + 16200704); // 32 KB  [n=128][k=128]
    unsigned short* Wt2 = (unsigned short*)(w + 16233472); // 16 KB  [n=64][k=128]
    unsigned short* h1s = (unsigned short*)(w + 16249856); // 12.81 MB (50048 rows, pad zeroed)
    unsigned short* h2s = (unsigned short*)(w + 29062144); // 6.41 MB  (50048 rows, pad zeroed)
    // total ws usage: ~35.5 MB

    k_prep     <<<96, 256, 0, stream>>>(W1, W2, Wt1, Wt2);
    k_csr_gemm1<<<NFILT + GEMM_BLOCKS, 256, 0, stream>>>(src, dst, counts, csr,
                                                         x, Wt1, h1s, h2s);
    k_agg1g2   <<<3125, 256, 0, stream>>>(h1s, Wt2, csr, counts, b1, h2s);
    k_agg2     <<<3125, 256, 0, stream>>>(h2s, csr, counts, b2, Wo, bo, out);
}

// Round 8
// 262.331 us; speedup vs baseline: 2.4861x; 2.4861x over previous
//
#include <hip/hip_runtime.h>
#include <stdint.h>

#define N_NODES 50000
#define N_EDGES 800000
#define CAP 80        // final CSR capacity; deg ~ Poisson(16), P(deg>80) ~ 1e-25
#define ZROW N_NODES  // zero-row index used to pad gather loops (rows 50000..50047 zeroed)
#define NRANGE 98     // node ranges: 98 x 512 = 50176 covers nodes+pads
#define NCHUNK 8      // edge chunks: 8 x 100000 edges
#define CHUNK_I4 25000    // int4 records per chunk
#define NFILT (NRANGE * NCHUNK)   // 784 filter blocks
#define GEMM_BLOCKS 782   // 50048/64
// R8: ownership CSR (zero device-scope atomics) with the R7 latency bug fixed:
// 784 (range x chunk) blocks, 25 iters x 4-batched independent loads (4-deep MLP)
// instead of 98 blocks x 781 serial-latency iters. Per-(node,chunk) sub-lists in
// csrc[node][chunk][16] (slot0=count), merged by k_merge into ushort csr + counts.
// D_IN=128, H1=128, H2=64, C=2 — inputs fp32; intermediates bf16 (h1s UNscaled, h2s dinv-prescaled)

typedef __attribute__((ext_vector_type(8))) short short8;     // 8 bf16 (4 VGPRs)
typedef __attribute__((ext_vector_type(4))) float floatx4;    // MFMA acc

// ---------- bf16 helpers ----------
__device__ __forceinline__ float bflo(uint32_t u) { return __uint_as_float(u << 16); }
__device__ __forceinline__ float bfhi(uint32_t u) { return __uint_as_float(u & 0xffff0000u); }
__device__ __forceinline__ unsigned short f2b(float f) {
    uint32_t u = __float_as_uint(f);
    u += 0x7fffu + ((u >> 16) & 1u);   // RNE
    return (unsigned short)(u >> 16);
}

// ---------- 1. prep: Wt1/Wt2 bf16 transposes only ----------
__global__ __launch_bounds__(256) void k_prep(const float* __restrict__ W1,
                                              const float* __restrict__ W2,
                                              unsigned short* __restrict__ Wt1,
                                              unsigned short* __restrict__ Wt2) {
    int gid = blockIdx.x * 256 + threadIdx.x;
    if (gid < 16384) {                     // Wt1[n][k] = bf16(W1[k][n])
        int k = gid >> 7, n = gid & 127;
        Wt1[n * 128 + k] = f2b(W1[gid]);
    } else if (gid < 24576) {              // Wt2[n][k] = bf16(W2[k][n])
        int j = gid - 16384;
        int k = j >> 6, n = j & 63;
        Wt2[n * 128 + k] = f2b(W2[j]);
    }
}

// ---------- 2. FUSED: filter-CSR (blocks 0..783) || gemm1 (784..1565) ----------
// filter block (r,c): owns nodes [r*512, r*512+512) for edge chunk c. Streams
// 25000 int4 dst records with 4-deep explicit load batching; hits -> LDS rank ->
// csrc[node][c][1+rk] (single-writer window, no device atomics).
// gemm1: h1s[v] = bf16(x[v]) @ bf16(W1), UNSCALED; 64 rows/block; zeroes pad rows.
__global__ __launch_bounds__(256) void k_filt_gemm1(const int* __restrict__ src,
                                                    const int* __restrict__ dst,
                                                    unsigned short* __restrict__ csrc,
                                                    const float* __restrict__ x,
                                                    const unsigned short* __restrict__ Wt1,
                                                    unsigned short* __restrict__ h1s,
                                                    unsigned short* __restrict__ h2s) {
    __shared__ unsigned short At[64 * 136];   // 17.0 KB (pad 8 bf16)
    __shared__ unsigned short Bt[128 * 136];  // 34.0 KB
    int t = threadIdx.x;
    if (blockIdx.x < NFILT) {
        int* cnt = (int*)At;                  // alias: 512 ints in At's LDS
        cnt[t] = 0; cnt[t + 256] = 0;
        __syncthreads();
        int r = blockIdx.x >> 3, c = blockIdx.x & 7;
        int node0 = r << 9;
        int cc16 = c << 4;
        const int4* d4 = (const int4*)dst + c * CHUNK_I4;
        const int4* s4 = (const int4*)src + c * CHUNK_I4;
#define FPROC(dv, j, g)                                                                                      \
        if (g) {                                                                                             \
            unsigned o0 = (unsigned)(dv.x - node0), o1 = (unsigned)(dv.y - node0);                           \
            unsigned o2 = (unsigned)(dv.z - node0), o3 = (unsigned)(dv.w - node0);                           \
            if ((o0 < 512u) || (o1 < 512u) || (o2 < 512u) || (o3 < 512u)) {                                  \
                int4 sv = s4[j];                                                                             \
                if (o0 < 512u) { int rk = atomicAdd(&cnt[o0], 1);                                            \
                    if (rk < 15) csrc[dv.x * 128 + cc16 + 1 + rk] = (unsigned short)sv.x; }                  \
                if (o1 < 512u) { int rk = atomicAdd(&cnt[o1], 1);                                            \
                    if (rk < 15) csrc[dv.y * 128 + cc16 + 1 + rk] = (unsigned short)sv.y; }                  \
                if (o2 < 512u) { int rk = atomicAdd(&cnt[o2], 1);                                            \
                    if (rk < 15) csrc[dv.z * 128 + cc16 + 1 + rk] = (unsigned short)sv.z; }                  \
                if (o3 < 512u) { int rk = atomicAdd(&cnt[o3], 1);                                            \
                    if (rk < 15) csrc[dv.w * 128 + cc16 + 1 + rk] = (unsigned short)sv.w; }                  \
            }                                                                                                \
        }
        for (int jj = 0; jj < 25; jj++) {     // 25 x 1024 covers 25000 int4s
            int j0 = (jj << 10) + t;
            int4 dA = {0,0,0,0}, dB = {0,0,0,0}, dC = {0,0,0,0}, dD = {0,0,0,0};
            bool gA = j0 < CHUNK_I4, gB = j0 + 256 < CHUNK_I4;
            bool gC = j0 + 512 < CHUNK_I4, gD = j0 + 768 < CHUNK_I4;
            if (gA) dA = d4[j0];              // 4 independent loads in flight (MLP)
            if (gB) dB = d4[j0 + 256];
            if (gC) dC = d4[j0 + 512];
            if (gD) dD = d4[j0 + 768];
            FPROC(dA, j0, gA)
            FPROC(dB, j0 + 256, gB)
            FPROC(dC, j0 + 512, gC)
            FPROC(dD, j0 + 768, gD)
        }
#undef FPROC
        __syncthreads();
        for (int i = t; i < 512; i += 256)    // count slots (0 for untouched nodes)
            csrc[(node0 + i) * 128 + cc16] = (unsigned short)cnt[i];
        return;
    }
    // ---- gemm1 ----
    int row0 = (blockIdx.x - NFILT) * 64;
    for (int i = t; i < 2048; i += 256) {     // stage Bt (Wt1 [n][k] bf16)
        int n = i >> 4, kc = (i & 15) * 8;
        *(uint4*)&Bt[n * 136 + kc] = *(const uint4*)(Wt1 + n * 128 + kc);
    }
    for (int i = t; i < 1024; i += 256) {     // stage At: fp32 -> bf16
        int r = i >> 4, kc = (i & 15) * 8;
        int g = row0 + r; if (g >= N_NODES) g = N_NODES - 1;
        const float* p = x + g * 128 + kc;
        float4 a = *(const float4*)p, b = *(const float4*)(p + 4);
        uint4 o;
        o.x = (uint32_t)f2b(a.x) | ((uint32_t)f2b(a.y) << 16);
        o.y = (uint32_t)f2b(a.z) | ((uint32_t)f2b(a.w) << 16);
        o.z = (uint32_t)f2b(b.x) | ((uint32_t)f2b(b.y) << 16);
        o.w = (uint32_t)f2b(b.z) | ((uint32_t)f2b(b.w) << 16);
        *(uint4*)&At[r * 136 + kc] = o;
    }
    __syncthreads();
    int wv = t >> 6, lane = t & 63;
    int m = lane & 15, qd = lane >> 4;
    floatx4 acc[8];
    #pragma unroll
    for (int c = 0; c < 8; c++) acc[c] = (floatx4){0.f, 0.f, 0.f, 0.f};
    const unsigned short* ap = &At[(wv * 16 + m) * 136 + qd * 8];
    const unsigned short* bp = &Bt[m * 136 + qd * 8];
    #pragma unroll
    for (int kk = 0; kk < 4; kk++) {
        short8 af = *(const short8*)(ap + kk * 32);
        #pragma unroll
        for (int c = 0; c < 8; c++) {
            short8 bf = *(const short8*)(bp + c * 16 * 136 + kk * 32);
            acc[c] = __builtin_amdgcn_mfma_f32_16x16x32_bf16(af, bf, acc[c], 0, 0, 0);
        }
    }
    #pragma unroll
    for (int reg = 0; reg < 4; reg++) {       // D[row=qd*4+reg][col=16c+m]
        int g = row0 + wv * 16 + qd * 4 + reg;
        if (g < N_NODES) {
            #pragma unroll
            for (int c = 0; c < 8; c++)
                h1s[g * 128 + c * 16 + m] = f2b(acc[c][reg]);
        } else {                              // zero pad rows (branchless-agg target)
            #pragma unroll
            for (int c = 0; c < 8; c++)
                h1s[g * 128 + c * 16 + m] = 0;
            #pragma unroll
            for (int c = 0; c < 4; c++)
                h2s[g * 64 + c * 16 + m] = 0;
        }
    }
}

// ---------- 3. merge: csrc[node][8][16] -> csr[node][80] ushort + counts ----------
// 1 thread/node: 8 contiguous 32B sub-rows (256B total), compile-time-unrolled
// predicated compaction. counts = true degree (sum of raw chunk counts).
__global__ __launch_bounds__(256) void k_merge(const unsigned short* __restrict__ csrc,
                                               unsigned short* __restrict__ csr,
                                               int* __restrict__ counts) {
    int v = blockIdx.x * 256 + threadIdx.x;   // 196*256 = 50176 (incl. pads)
    const uint4* row = (const uint4*)(csrc + v * 128);
    unsigned short* out = csr + v * CAP;
    int pos = 0, total = 0;
    #pragma unroll
    for (int c = 0; c < 8; c++) {
        uint4 A = row[c * 2], B = row[c * 2 + 1];
        int cc = (int)(A.x & 0xffffu);        // slot 0 = chunk count
        int cw = min(cc, 15);
#define PUT(k, val) if (k < cw && pos + k < CAP) out[pos + k] = (unsigned short)(val);
        PUT(0,  A.x >> 16)
        PUT(1,  A.y & 0xffffu)  PUT(2,  A.y >> 16)
        PUT(3,  A.z & 0xffffu)  PUT(4,  A.z >> 16)
        PUT(5,  A.w & 0xffffu)  PUT(6,  A.w >> 16)
        PUT(7,  B.x & 0xffffu)  PUT(8,  B.x >> 16)
        PUT(9,  B.y & 0xffffu)  PUT(10, B.y >> 16)
        PUT(11, B.z & 0xffffu)  PUT(12, B.z >> 16)
        PUT(13, B.w & 0xffffu)  PUT(14, B.w >> 16)
#undef PUT
        pos += cw; total += cc;
    }
    counts[v] = total;
}

// ---------- 4. fused agg1 + GEMM2 (csr now ushort) ----------
__global__ __launch_bounds__(256) void k_agg1g2(const unsigned short* __restrict__ h1s,
                                                const unsigned short* __restrict__ Wt2,
                                                const unsigned short* __restrict__ csr,
                                                const int* __restrict__ counts,
                                                const float* __restrict__ b1,
                                                unsigned short* __restrict__ h2s) {
    __shared__ unsigned short Bt[64 * 136];   // Wt2 [n=64][k=128] staged
    __shared__ unsigned short At[16 * 136];   // r1 tile [16 rows][128 k]
    int t = threadIdx.x;
    for (int i = t; i < 1024; i += 256) {     // stage Bt2
        int n = i >> 4, kc = (i & 15) * 8;
        *(uint4*)&Bt[n * 136 + kc] = *(const uint4*)(Wt2 + n * 128 + kc);
    }
    int wv = t >> 6, lane = t & 63;
    int q = lane >> 4, l = lane & 15;
    int v0 = blockIdx.x * 16;
    int v = v0 + wv * 4 + q;                  // 50000 = 3125*16: always valid
    int n = counts[v];
    float dv = rsqrtf((float)n + 1.0f);
    int n_eff = min(n, CAP);
    const unsigned short* cs = csr + v * CAP;
    int nmax = n_eff;
    nmax = max(nmax, __shfl_xor(nmax, 16));
    nmax = max(nmax, __shfl_xor(nmax, 32));
    float a0, a1, a2, a3, a4, a5, a6, a7;
    {   // self-loop row: dv * h1s[v] (h1s unscaled)
        uint4 p = *(const uint4*)(h1s + v * 128 + l * 8);
        a0 = dv * bflo(p.x); a1 = dv * bfhi(p.x); a2 = dv * bflo(p.y); a3 = dv * bfhi(p.y);
        a4 = dv * bflo(p.z); a5 = dv * bfhi(p.z); a6 = dv * bflo(p.w); a7 = dv * bfhi(p.w);
    }
    for (int base = 0; base < nmax; base += 16) {
        int idx = base + l;
        int e = (idx < n_eff) ? (int)cs[idx] : ZROW;   // pad -> zero row
        float de = rsqrtf((float)counts[e] + 1.0f);    // counts[ZROW]=0 -> de=1, row=0
        int mm = nmax - base; if (mm > 16) mm = 16;
        #pragma unroll 4
        for (int i = 0; i < mm; i++) {
            int s = __shfl(e, (q << 4) + i);           // ZROW contributes exact 0.0f
            float di = __shfl(de, (q << 4) + i);
            uint4 p = *(const uint4*)(h1s + s * 128 + l * 8);
            a0 = fmaf(di, bflo(p.x), a0); a1 = fmaf(di, bfhi(p.x), a1);
            a2 = fmaf(di, bflo(p.y), a2); a3 = fmaf(di, bfhi(p.y), a3);
            a4 = fmaf(di, bflo(p.z), a4); a5 = fmaf(di, bfhi(p.z), a5);
            a6 = fmaf(di, bflo(p.w), a6); a7 = fmaf(di, bfhi(p.w), a7);
        }
    }
    {
        float4 bL = *(const float4*)(b1 + l * 8);
        float4 bH = *(const float4*)(b1 + l * 8 + 4);
        a0 = fmaxf(fmaf(dv, a0, bL.x), 0.f); a1 = fmaxf(fmaf(dv, a1, bL.y), 0.f);
        a2 = fmaxf(fmaf(dv, a2, bL.z), 0.f); a3 = fmaxf(fmaf(dv, a3, bL.w), 0.f);
        a4 = fmaxf(fmaf(dv, a4, bH.x), 0.f); a5 = fmaxf(fmaf(dv, a5, bH.y), 0.f);
        a6 = fmaxf(fmaf(dv, a6, bH.z), 0.f); a7 = fmaxf(fmaf(dv, a7, bH.w), 0.f);
        uint4 o;
        o.x = (uint32_t)f2b(a0) | ((uint32_t)f2b(a1) << 16);
        o.y = (uint32_t)f2b(a2) | ((uint32_t)f2b(a3) << 16);
        o.z = (uint32_t)f2b(a4) | ((uint32_t)f2b(a5) << 16);
        o.w = (uint32_t)f2b(a6) | ((uint32_t)f2b(a7) << 16);
        *(uint4*)&At[(wv * 4 + q) * 136 + l * 8] = o;   // r1 tile row
    }
    __syncthreads();
    // MFMA: wave wv -> col-tile wv (cols 16wv..16wv+15)
    int m = lane & 15, qd = lane >> 4;
    floatx4 acc = (floatx4){0.f, 0.f, 0.f, 0.f};
    const unsigned short* ap = &At[m * 136 + qd * 8];
    const unsigned short* bp = &Bt[(wv * 16 + m) * 136 + qd * 8];
    #pragma unroll
    for (int kk = 0; kk < 4; kk++) {
        short8 af = *(const short8*)(ap + kk * 32);
        short8 bf = *(const short8*)(bp + kk * 32);
        acc = __builtin_amdgcn_mfma_f32_16x16x32_bf16(af, bf, acc, 0, 0, 0);
    }
    #pragma unroll
    for (int reg = 0; reg < 4; reg++) {
        int g = v0 + qd * 4 + reg;
        float dg = rsqrtf((float)counts[g] + 1.0f);   // prescale h2 rows
        h2s[g * 64 + wv * 16 + m] = f2b(dg * acc[reg]);
    }
}

// ---------- 5. agg2 + head (2 neighbors/iter; csr ushort) ----------
__global__ __launch_bounds__(256) void k_agg2(const unsigned short* __restrict__ h2s,
                                              const unsigned short* __restrict__ csr,
                                              const int* __restrict__ counts,
                                              const float* __restrict__ b2,
                                              const float* __restrict__ Wo,
                                              const float* __restrict__ bo,
                                              float* __restrict__ out) {
    int wave = (blockIdx.x * 256 + threadIdx.x) >> 6;
    int lane = threadIdx.x & 63;
    int q = lane >> 4, l = lane & 15;
    int h = l >> 3, c = l & 7;                // half, column-octet
    int v = wave * 4 + q;                     // 3125*4*4 = 50000: always valid
    int n = counts[v];
    float dv = rsqrtf((float)n + 1.0f);
    int n_eff = min(n, CAP);
    const unsigned short* cs = csr + v * CAP;
    int nmax = n_eff;
    nmax = max(nmax, __shfl_xor(nmax, 16));
    nmax = max(nmax, __shfl_xor(nmax, 32));
    float a0 = 0.f, a1 = 0.f, a2 = 0.f, a3 = 0.f, a4 = 0.f, a5 = 0.f, a6 = 0.f, a7 = 0.f;
    if (h == 0) {   // self-loop row (prescaled) into half 0 only
        uint4 p = *(const uint4*)(h2s + v * 64 + c * 8);
        a0 = bflo(p.x); a1 = bfhi(p.x); a2 = bflo(p.y); a3 = bfhi(p.y);
        a4 = bflo(p.z); a5 = bfhi(p.z); a6 = bflo(p.w); a7 = bfhi(p.w);
    }
    for (int base = 0; base < nmax; base += 16) {
        int idx = base + l;
        int e = (idx < n_eff) ? (int)cs[idx] : ZROW;   // pad -> zero row
        int mm = nmax - base; if (mm > 16) mm = 16;
        int pairs = (mm + 1) >> 1;
        #pragma unroll 4
        for (int i = 0; i < pairs; i++) {
            int s = __shfl(e, (q << 4) + 2 * i + h);   // half h takes pair element h
            uint4 p = *(const uint4*)(h2s + s * 64 + c * 8);
            a0 += bflo(p.x); a1 += bfhi(p.x); a2 += bflo(p.y); a3 += bfhi(p.y);
            a4 += bflo(p.z); a5 += bfhi(p.z); a6 += bflo(p.w); a7 += bfhi(p.w);
        }
    }
    // combine halves
    a0 += __shfl_xor(a0, 8); a1 += __shfl_xor(a1, 8);
    a2 += __shfl_xor(a2, 8); a3 += __shfl_xor(a3, 8);
    a4 += __shfl_xor(a4, 8); a5 += __shfl_xor(a5, 8);
    a6 += __shfl_xor(a6, 8); a7 += __shfl_xor(a7, 8);
    float4 bL = *(const float4*)(b2 + c * 8);
    float4 bH = *(const float4*)(b2 + c * 8 + 4);
    a0 = fmaxf(fmaf(dv, a0, bL.x), 0.f); a1 = fmaxf(fmaf(dv, a1, bL.y), 0.f);
    a2 = fmaxf(fmaf(dv, a2, bL.z), 0.f); a3 = fmaxf(fmaf(dv, a3, bL.w), 0.f);
    a4 = fmaxf(fmaf(dv, a4, bH.x), 0.f); a5 = fmaxf(fmaf(dv, a5, bH.y), 0.f);
    a6 = fmaxf(fmaf(dv, a6, bH.z), 0.f); a7 = fmaxf(fmaf(dv, a7, bH.w), 0.f);
    // head: logits over this lane's 8 cols (8c..8c+7), Wo row-major [64][2]
    float4 wA = *(const float4*)(Wo + c * 16);
    float4 wB = *(const float4*)(Wo + c * 16 + 4);
    float4 wC = *(const float4*)(Wo + c * 16 + 8);
    float4 wD = *(const float4*)(Wo + c * 16 + 12);
    float l0 = a0 * wA.x + a1 * wA.z + a2 * wB.x + a3 * wB.z
             + a4 * wC.x + a5 * wC.z + a6 * wD.x + a7 * wD.z;
    float l1 = a0 * wA.y + a1 * wA.w + a2 * wB.y + a3 * wB.w
             + a4 * wC.y + a5 * wC.w + a6 * wD.y + a7 * wD.w;
    l0 += __shfl_xor(l0, 1); l1 += __shfl_xor(l1, 1);
    l0 += __shfl_xor(l0, 2); l1 += __shfl_xor(l1, 2);
    l0 += __shfl_xor(l0, 4); l1 += __shfl_xor(l1, 4);
    if (l == 0) {
        float2 bof = *(const float2*)bo;
        l0 += bof.x; l1 += bof.y;
        float m = fmaxf(l0, l1);
        float ls = m + __logf(__expf(l0 - m) + __expf(l1 - m));
        *(float2*)(out + v * 2) = make_float2(l0 - ls, l1 - ls);
    }
}

extern "C" void kernel_launch(void* const* d_in, const int* in_sizes, int n_in,
                              void* d_out, int out_size, void* d_ws, size_t ws_size,
                              hipStream_t stream) {
    const float* x  = (const float*)d_in[0];
    const int* ei   = (const int*)d_in[1];
    const float* W1 = (const float*)d_in[2];
    const float* b1 = (const float*)d_in[3];
    const float* W2 = (const float*)d_in[4];
    const float* b2 = (const float*)d_in[5];
    const float* Wo = (const float*)d_in[6];
    const float* bo = (const float*)d_in[7];
    float* out      = (float*)d_out;
    const int* src = ei;             // edge_index[0]
    const int* dst = ei + N_EDGES;   // edge_index[1]

    char* w = (char*)d_ws;
    int* counts = (int*)(w + 0);                             // 200 KB (50176 ints, by k_merge)
    unsigned short* csr = (unsigned short*)(w + 200704);     // 8.03 MB [node][80] ushort
    unsigned short* Wt1 = (unsigned short*)(w + 8228864);    // 32 KB  [n=128][k=128]
    unsigned short* Wt2 = (unsigned short*)(w + 8261632);    // 16 KB  [n=64][k=128]
    unsigned short* h1s = (unsigned short*)(w + 8278016);    // 12.81 MB (50048 rows, pad zeroed)
    unsigned short* h2s = (unsigned short*)(w + 21090304);   // 6.41 MB  (50048 rows, pad zeroed)
    unsigned short* csrc = (unsigned short*)(w + 27496448);  // 12.85 MB [node][8][16] sub-lists
    // total ws usage: ~40.3 MB

    k_prep      <<<96, 256, 0, stream>>>(W1, W2, Wt1, Wt2);
    k_filt_gemm1<<<NFILT + GEMM_BLOCKS, 256, 0, stream>>>(src, dst, csrc,
                                                          x, Wt1, h1s, h2s);
    k_merge     <<<196, 256, 0, stream>>>(csrc, csr, counts);
    k_agg1g2    <<<3125, 256, 0, stream>>>(h1s, Wt2, csr, counts, b1, h2s);
    k_agg2      <<<3125, 256, 0, stream>>>(h2s, csr, counts, b2, Wo, bo, out);
}

// Round 9
// 166.054 us; speedup vs baseline: 3.9275x; 1.5798x over previous
//
#include <hip/hip_runtime.h>
#include <stdint.h>

#define N_NODES 50000
#define N_EDGES 800000
#define CAP 80        // final CSR capacity; deg ~ Poisson(16), P(deg>80) ~ 1e-25
#define ZROW N_NODES  // zero-row index used to pad gather loops (rows 50000..50047 zeroed)
#define NBKT 196      // buckets: bucket = dst>>8; 196*256 = 50176 covers nodes+pads
#define BKT_CAP 4608  // bucket window slots; bucket edges ~ Poisson(4082), +8 sigma
#define NSCAT 256     // binscat blocks, 3125 edges each
#define EPB 3125      // edges per binscat block
#define GEMM_BLOCKS 782   // 50048/64
// R9: CSR build via single-pass atomic-RESERVATION binning. Device atomics: 1.6M
// (R0-R4 scat, 52us txn-bound) -> 50K (196 bucket reservations x 256 blocks). Per
// block: LDS hist -> reserve window range -> LDS-cursor scatter of packed 4B
// records (src:16|doff:8<<16) into slack-padded per-bucket windows. k_csr then
// builds ushort CSR per bucket from its contiguous window (L2-local 40KB writes).
// R5/R6's deterministic version needed 4 stages (hist,scan,binscat,csr) = null;
// this is 2 stages, binscat fused under gemm1. R7/R8 redundant-stream: dead.
// D_IN=128, H1=128, H2=64, C=2 — inputs fp32; intermediates bf16 (h1s UNscaled, h2s dinv-prescaled)

typedef __attribute__((ext_vector_type(8))) short short8;     // 8 bf16 (4 VGPRs)
typedef __attribute__((ext_vector_type(4))) float floatx4;    // MFMA acc

// ---------- bf16 helpers ----------
__device__ __forceinline__ float bflo(uint32_t u) { return __uint_as_float(u << 16); }
__device__ __forceinline__ float bfhi(uint32_t u) { return __uint_as_float(u & 0xffff0000u); }
__device__ __forceinline__ unsigned short f2b(float f) {
    uint32_t u = __float_as_uint(f);
    u += 0x7fffu + ((u >> 16) & 1u);   // RNE
    return (unsigned short)(u >> 16);
}

// ---------- 1. prep: Wt1/Wt2 bf16 transposes + zero gcnt[196] ----------
__global__ __launch_bounds__(256) void k_prep(const float* __restrict__ W1,
                                              const float* __restrict__ W2,
                                              unsigned short* __restrict__ Wt1,
                                              unsigned short* __restrict__ Wt2,
                                              int* __restrict__ gcnt) {
    int gid = blockIdx.x * 256 + threadIdx.x;
    if (gid < 16384) {                     // Wt1[n][k] = bf16(W1[k][n])
        int k = gid >> 7, n = gid & 127;
        Wt1[n * 128 + k] = f2b(W1[gid]);
    } else if (gid < 24576) {              // Wt2[n][k] = bf16(W2[k][n])
        int j = gid - 16384;
        int k = j >> 6, n = j & 63;
        Wt2[n * 128 + k] = f2b(W2[j]);
    } else if (gid < 24576 + NBKT) {       // zero bucket cursors
        gcnt[gid - 24576] = 0;
    }
}

// ---------- 2. FUSED: binscat (blocks 0..255) || gemm1 (256..1037) ----------
// binscat block: 3125 edges. Pass A: LDS hist[196]. Reserve: 196 device atomics
// (50K total, ~2us at measured 35G txn/s). Pass B: LDS-cursor scatter of packed
// records into binned[bucket*4608 ..]. No per-edge device atomics.
// gemm1: h1s[v] = bf16(x[v]) @ bf16(W1), UNSCALED; 64 rows/block; zeroes pad rows.
__global__ __launch_bounds__(256) void k_binscat_gemm1(const int* __restrict__ src,
                                                       const int* __restrict__ dst,
                                                       int* __restrict__ gcnt,
                                                       uint32_t* __restrict__ binned,
                                                       const float* __restrict__ x,
                                                       const unsigned short* __restrict__ Wt1,
                                                       unsigned short* __restrict__ h1s,
                                                       unsigned short* __restrict__ h2s) {
    __shared__ unsigned short At[64 * 136];   // 17.0 KB (pad 8 bf16)
    __shared__ unsigned short Bt[128 * 136];  // 34.0 KB
    int t = threadIdx.x;
    if (blockIdx.x < NSCAT) {
        int* hist = (int*)At;                 // [196] histogram
        int* cur  = ((int*)At) + 256;         // [196] global write cursors
        if (t < NBKT) hist[t] = 0;
        __syncthreads();
        int e0 = blockIdx.x * EPB;
        for (int i = t; i < EPB; i += 256)    // pass A: histogram (13 iters)
            atomicAdd(&hist[dst[e0 + i] >> 8], 1);
        __syncthreads();
        if (t < NBKT) {                       // reserve per-bucket ranges
            int h = hist[t];
            int off = h ? atomicAdd(&gcnt[t], h) : 0;   // device atomic (196/block)
            cur[t] = t * BKT_CAP + off;
        }
        __syncthreads();
        for (int i = t; i < EPB; i += 256) {  // pass B: scatter packed records
            int d = dst[e0 + i], s = src[e0 + i];
            int bb = d >> 8;
            int idx = atomicAdd(&cur[bb], 1); // LDS atomic
            if (idx < (bb + 1) * BKT_CAP)     // slack clamp (P(overflow) ~ 0)
                binned[idx] = (uint32_t)s | ((uint32_t)(d & 255) << 16);
        }
        return;
    }
    // ---- gemm1 ----
    int row0 = (blockIdx.x - NSCAT) * 64;
    for (int i = t; i < 2048; i += 256) {     // stage Bt (Wt1 [n][k] bf16)
        int n = i >> 4, kc = (i & 15) * 8;
        *(uint4*)&Bt[n * 136 + kc] = *(const uint4*)(Wt1 + n * 128 + kc);
    }
    for (int i = t; i < 1024; i += 256) {     // stage At: fp32 -> bf16
        int r = i >> 4, kc = (i & 15) * 8;
        int g = row0 + r; if (g >= N_NODES) g = N_NODES - 1;
        const float* p = x + g * 128 + kc;
        float4 a = *(const float4*)p, b = *(const float4*)(p + 4);
        uint4 o;
        o.x = (uint32_t)f2b(a.x) | ((uint32_t)f2b(a.y) << 16);
        o.y = (uint32_t)f2b(a.z) | ((uint32_t)f2b(a.w) << 16);
        o.z = (uint32_t)f2b(b.x) | ((uint32_t)f2b(b.y) << 16);
        o.w = (uint32_t)f2b(b.z) | ((uint32_t)f2b(b.w) << 16);
        *(uint4*)&At[r * 136 + kc] = o;
    }
    __syncthreads();
    int wv = t >> 6, lane = t & 63;
    int m = lane & 15, qd = lane >> 4;
    floatx4 acc[8];
    #pragma unroll
    for (int c = 0; c < 8; c++) acc[c] = (floatx4){0.f, 0.f, 0.f, 0.f};
    const unsigned short* ap = &At[(wv * 16 + m) * 136 + qd * 8];
    const unsigned short* bp = &Bt[m * 136 + qd * 8];
    #pragma unroll
    for (int kk = 0; kk < 4; kk++) {
        short8 af = *(const short8*)(ap + kk * 32);
        #pragma unroll
        for (int c = 0; c < 8; c++) {
            short8 bf = *(const short8*)(bp + c * 16 * 136 + kk * 32);
            acc[c] = __builtin_amdgcn_mfma_f32_16x16x32_bf16(af, bf, acc[c], 0, 0, 0);
        }
    }
    #pragma unroll
    for (int reg = 0; reg < 4; reg++) {       // D[row=qd*4+reg][col=16c+m]
        int g = row0 + wv * 16 + qd * 4 + reg;
        if (g < N_NODES) {
            #pragma unroll
            for (int c = 0; c < 8; c++)
                h1s[g * 128 + c * 16 + m] = f2b(acc[c][reg]);
        } else {                              // zero pad rows (branchless-agg target)
            #pragma unroll
            for (int c = 0; c < 8; c++)
                h1s[g * 128 + c * 16 + m] = 0;
            #pragma unroll
            for (int c = 0; c < 4; c++)
                h2s[g * 64 + c * 16 + m] = 0;
        }
    }
}

// ---------- 3. per-bucket CSR: bucket window -> ushort csr + counts ----------
// Block b: read its contiguous window (coalesced, ~16 iters), LDS-atomic rank,
// write 2B srcs into the bucket's 256-node x 160B csr region (40KB, L2-local).
__global__ __launch_bounds__(256) void k_csr(const uint32_t* __restrict__ binned,
                                             const int* __restrict__ gcnt,
                                             unsigned short* __restrict__ csr,
                                             int* __restrict__ counts) {
    __shared__ int cnt[256];
    int t = threadIdx.x, b = blockIdx.x;
    cnt[t] = 0;
    __syncthreads();
    int n = min(gcnt[b], BKT_CAP);
    int node0 = b << 8;
    const uint32_t* w0 = binned + b * BKT_CAP;
    for (int i = t; i < n; i += 256) {
        uint32_t w = w0[i];
        int doff = (int)(w >> 16);
        int r = atomicAdd(&cnt[doff], 1);    // LDS atomic rank
        if (r < CAP) csr[(node0 + doff) * CAP + r] = (unsigned short)(w & 0xffffu);
    }
    __syncthreads();
    counts[node0 + t] = cnt[t];              // covers all 50176 incl. zero pads
}

// ---------- 4. fused agg1 + GEMM2 (ushort csr; verified R8) ----------
__global__ __launch_bounds__(256) void k_agg1g2(const unsigned short* __restrict__ h1s,
                                                const unsigned short* __restrict__ Wt2,
                                                const unsigned short* __restrict__ csr,
                                                const int* __restrict__ counts,
                                                const float* __restrict__ b1,
                                                unsigned short* __restrict__ h2s) {
    __shared__ unsigned short Bt[64 * 136];   // Wt2 [n=64][k=128] staged
    __shared__ unsigned short At[16 * 136];   // r1 tile [16 rows][128 k]
    int t = threadIdx.x;
    for (int i = t; i < 1024; i += 256) {     // stage Bt2
        int n = i >> 4, kc = (i & 15) * 8;
        *(uint4*)&Bt[n * 136 + kc] = *(const uint4*)(Wt2 + n * 128 + kc);
    }
    int wv = t >> 6, lane = t & 63;
    int q = lane >> 4, l = lane & 15;
    int v0 = blockIdx.x * 16;
    int v = v0 + wv * 4 + q;                  // 50000 = 3125*16: always valid
    int n = counts[v];
    float dv = rsqrtf((float)n + 1.0f);
    int n_eff = min(n, CAP);
    const unsigned short* cs = csr + v * CAP;
    int nmax = n_eff;
    nmax = max(nmax, __shfl_xor(nmax, 16));
    nmax = max(nmax, __shfl_xor(nmax, 32));
    float a0, a1, a2, a3, a4, a5, a6, a7;
    {   // self-loop row: dv * h1s[v] (h1s unscaled)
        uint4 p = *(const uint4*)(h1s + v * 128 + l * 8);
        a0 = dv * bflo(p.x); a1 = dv * bfhi(p.x); a2 = dv * bflo(p.y); a3 = dv * bfhi(p.y);
        a4 = dv * bflo(p.z); a5 = dv * bfhi(p.z); a6 = dv * bflo(p.w); a7 = dv * bfhi(p.w);
    }
    for (int base = 0; base < nmax; base += 16) {
        int idx = base + l;
        int e = (idx < n_eff) ? (int)cs[idx] : ZROW;   // pad -> zero row
        float de = rsqrtf((float)counts[e] + 1.0f);    // counts[ZROW]=0 -> de=1, row=0
        int mm = nmax - base; if (mm > 16) mm = 16;
        #pragma unroll 4
        for (int i = 0; i < mm; i++) {
            int s = __shfl(e, (q << 4) + i);           // ZROW contributes exact 0.0f
            float di = __shfl(de, (q << 4) + i);
            uint4 p = *(const uint4*)(h1s + s * 128 + l * 8);
            a0 = fmaf(di, bflo(p.x), a0); a1 = fmaf(di, bfhi(p.x), a1);
            a2 = fmaf(di, bflo(p.y), a2); a3 = fmaf(di, bfhi(p.y), a3);
            a4 = fmaf(di, bflo(p.z), a4); a5 = fmaf(di, bfhi(p.z), a5);
            a6 = fmaf(di, bflo(p.w), a6); a7 = fmaf(di, bfhi(p.w), a7);
        }
    }
    {
        float4 bL = *(const float4*)(b1 + l * 8);
        float4 bH = *(const float4*)(b1 + l * 8 + 4);
        a0 = fmaxf(fmaf(dv, a0, bL.x), 0.f); a1 = fmaxf(fmaf(dv, a1, bL.y), 0.f);
        a2 = fmaxf(fmaf(dv, a2, bL.z), 0.f); a3 = fmaxf(fmaf(dv, a3, bL.w), 0.f);
        a4 = fmaxf(fmaf(dv, a4, bH.x), 0.f); a5 = fmaxf(fmaf(dv, a5, bH.y), 0.f);
        a6 = fmaxf(fmaf(dv, a6, bH.z), 0.f); a7 = fmaxf(fmaf(dv, a7, bH.w), 0.f);
        uint4 o;
        o.x = (uint32_t)f2b(a0) | ((uint32_t)f2b(a1) << 16);
        o.y = (uint32_t)f2b(a2) | ((uint32_t)f2b(a3) << 16);
        o.z = (uint32_t)f2b(a4) | ((uint32_t)f2b(a5) << 16);
        o.w = (uint32_t)f2b(a6) | ((uint32_t)f2b(a7) << 16);
        *(uint4*)&At[(wv * 4 + q) * 136 + l * 8] = o;   // r1 tile row
    }
    __syncthreads();
    // MFMA: wave wv -> col-tile wv (cols 16wv..16wv+15)
    int m = lane & 15, qd = lane >> 4;
    floatx4 acc = (floatx4){0.f, 0.f, 0.f, 0.f};
    const unsigned short* ap = &At[m * 136 + qd * 8];
    const unsigned short* bp = &Bt[(wv * 16 + m) * 136 + qd * 8];
    #pragma unroll
    for (int kk = 0; kk < 4; kk++) {
        short8 af = *(const short8*)(ap + kk * 32);
        short8 bf = *(const short8*)(bp + kk * 32);
        acc = __builtin_amdgcn_mfma_f32_16x16x32_bf16(af, bf, acc, 0, 0, 0);
    }
    #pragma unroll
    for (int reg = 0; reg < 4; reg++) {
        int g = v0 + qd * 4 + reg;
        float dg = rsqrtf((float)counts[g] + 1.0f);   // prescale h2 rows
        h2s[g * 64 + wv * 16 + m] = f2b(dg * acc[reg]);
    }
}

// ---------- 5. agg2 + head (2 neighbors/iter; ushort csr; verified R8) ----------
__global__ __launch_bounds__(256) void k_agg2(const unsigned short* __restrict__ h2s,
                                              const unsigned short* __restrict__ csr,
                                              const int* __restrict__ counts,
                                              const float* __restrict__ b2,
                                              const float* __restrict__ Wo,
                                              const float* __restrict__ bo,
                                              float* __restrict__ out) {
    int wave = (blockIdx.x * 256 + threadIdx.x) >> 6;
    int lane = threadIdx.x & 63;
    int q = lane >> 4, l = lane & 15;
    int h = l >> 3, c = l & 7;                // half, column-octet
    int v = wave * 4 + q;                     // 3125*4*4 = 50000: always valid
    int n = counts[v];
    float dv = rsqrtf((float)n + 1.0f);
    int n_eff = min(n, CAP);
    const unsigned short* cs = csr + v * CAP;
    int nmax = n_eff;
    nmax = max(nmax, __shfl_xor(nmax, 16));
    nmax = max(nmax, __shfl_xor(nmax, 32));
    float a0 = 0.f, a1 = 0.f, a2 = 0.f, a3 = 0.f, a4 = 0.f, a5 = 0.f, a6 = 0.f, a7 = 0.f;
    if (h == 0) {   // self-loop row (prescaled) into half 0 only
        uint4 p = *(const uint4*)(h2s + v * 64 + c * 8);
        a0 = bflo(p.x); a1 = bfhi(p.x); a2 = bflo(p.y); a3 = bfhi(p.y);
        a4 = bflo(p.z); a5 = bfhi(p.z); a6 = bflo(p.w); a7 = bfhi(p.w);
    }
    for (int base = 0; base < nmax; base += 16) {
        int idx = base + l;
        int e = (idx < n_eff) ? (int)cs[idx] : ZROW;   // pad -> zero row
        int mm = nmax - base; if (mm > 16) mm = 16;
        int pairs = (mm + 1) >> 1;
        #pragma unroll 4
        for (int i = 0; i < pairs; i++) {
            int s = __shfl(e, (q << 4) + 2 * i + h);   // half h takes pair element h
            uint4 p = *(const uint4*)(h2s + s * 64 + c * 8);
            a0 += bflo(p.x); a1 += bfhi(p.x); a2 += bflo(p.y); a3 += bfhi(p.y);
            a4 += bflo(p.z); a5 += bfhi(p.z); a6 += bflo(p.w); a7 += bfhi(p.w);
        }
    }
    // combine halves
    a0 += __shfl_xor(a0, 8); a1 += __shfl_xor(a1, 8);
    a2 += __shfl_xor(a2, 8); a3 += __shfl_xor(a3, 8);
    a4 += __shfl_xor(a4, 8); a5 += __shfl_xor(a5, 8);
    a6 += __shfl_xor(a6, 8); a7 += __shfl_xor(a7, 8);
    float4 bL = *(const float4*)(b2 + c * 8);
    float4 bH = *(const float4*)(b2 + c * 8 + 4);
    a0 = fmaxf(fmaf(dv, a0, bL.x), 0.f); a1 = fmaxf(fmaf(dv, a1, bL.y), 0.f);
    a2 = fmaxf(fmaf(dv, a2, bL.z), 0.f); a3 = fmaxf(fmaf(dv, a3, bL.w), 0.f);
    a4 = fmaxf(fmaf(dv, a4, bH.x), 0.f); a5 = fmaxf(fmaf(dv, a5, bH.y), 0.f);
    a6 = fmaxf(fmaf(dv, a6, bH.z), 0.f); a7 = fmaxf(fmaf(dv, a7, bH.w), 0.f);
    // head: logits over this lane's 8 cols (8c..8c+7), Wo row-major [64][2]
    float4 wA = *(const float4*)(Wo + c * 16);
    float4 wB = *(const float4*)(Wo + c * 16 + 4);
    float4 wC = *(const float4*)(Wo + c * 16 + 8);
    float4 wD = *(const float4*)(Wo + c * 16 + 12);
    float l0 = a0 * wA.x + a1 * wA.z + a2 * wB.x + a3 * wB.z
             + a4 * wC.x + a5 * wC.z + a6 * wD.x + a7 * wD.z;
    float l1 = a0 * wA.y + a1 * wA.w + a2 * wB.y + a3 * wB.w
             + a4 * wC.y + a5 * wC.w + a6 * wD.y + a7 * wD.w;
    l0 += __shfl_xor(l0, 1); l1 += __shfl_xor(l1, 1);
    l0 += __shfl_xor(l0, 2); l1 += __shfl_xor(l1, 2);
    l0 += __shfl_xor(l0, 4); l1 += __shfl_xor(l1, 4);
    if (l == 0) {
        float2 bof = *(const float2*)bo;
        l0 += bof.x; l1 += bof.y;
        float m = fmaxf(l0, l1);
        float ls = m + __logf(__expf(l0 - m) + __expf(l1 - m));
        *(float2*)(out + v * 2) = make_float2(l0 - ls, l1 - ls);
    }
}

extern "C" void kernel_launch(void* const* d_in, const int* in_sizes, int n_in,
                              void* d_out, int out_size, void* d_ws, size_t ws_size,
                              hipStream_t stream) {
    const float* x  = (const float*)d_in[0];
    const int* ei   = (const int*)d_in[1];
    const float* W1 = (const float*)d_in[2];
    const float* b1 = (const float*)d_in[3];
    const float* W2 = (const float*)d_in[4];
    const float* b2 = (const float*)d_in[5];
    const float* Wo = (const float*)d_in[6];
    const float* bo = (const float*)d_in[7];
    float* out      = (float*)d_out;
    const int* src = ei;             // edge_index[0]
    const int* dst = ei + N_EDGES;   // edge_index[1]

    char* w = (char*)d_ws;
    int* counts = (int*)(w + 0);                             // 200 KB (50176 ints, by k_csr)
    unsigned short* csr = (unsigned short*)(w + 200704);     // 8.03 MB [node][80] ushort
    unsigned short* Wt1 = (unsigned short*)(w + 8228864);    // 32 KB  [n=128][k=128]
    unsigned short* Wt2 = (unsigned short*)(w + 8261632);    // 16 KB  [n=64][k=128]
    unsigned short* h1s = (unsigned short*)(w + 8278016);    // 12.81 MB (50048 rows, pad zeroed)
    unsigned short* h2s = (unsigned short*)(w + 21090304);   // 6.41 MB  (50048 rows, pad zeroed)
    uint32_t* binned = (uint32_t*)(w + 27496448);            // 3.61 MB [196][4608] packed
    int* gcnt = (int*)(w + 31109120);                        // 784 B bucket cursors
    // total ws usage: ~31.1 MB

    k_prep         <<<97, 256, 0, stream>>>(W1, W2, Wt1, Wt2, gcnt);
    k_binscat_gemm1<<<NSCAT + GEMM_BLOCKS, 256, 0, stream>>>(src, dst, gcnt, binned,
                                                             x, Wt1, h1s, h2s);
    k_csr          <<<NBKT, 256, 0, stream>>>(binned, gcnt, csr, counts);
    k_agg1g2       <<<3125, 256, 0, stream>>>(h1s, Wt2, csr, counts, b1, h2s);
    k_agg2         <<<3125, 256, 0, stream>>>(h2s, csr, counts, b2, Wo, bo, out);
}